// Round 17
// baseline (147.548 us; speedup 1.0000x reference)
//
#include <hip/hip_runtime.h>
#include <hip/hip_bf16.h>
#include <cstdint>
#include <climits>

#define TT 4096
#define DD 512
#define HH 8
#define HD 64
#define WW 16
#define CDEPTH 8

typedef unsigned short ushortT;
typedef unsigned int uintT;
using bf16x8 = __attribute__((ext_vector_type(8))) short;
using f32x4  = __attribute__((ext_vector_type(4))) float;

static __device__ __forceinline__ uintT f2bf(float v) {
    __hip_bfloat16 h = __float2bfloat16(v);
    return (uintT)*reinterpret_cast<ushortT*>(&h);
}
static __device__ __forceinline__ float bf2f(uintT u) {
    return __uint_as_float(u << 16);
}

// Swizzled LDS index (in shorts) for [row][32 shorts] tiles merged as 128B super-rows.
// r = logical row, c = 16B-chunk index (0..3). Bijective; verified conflict-free
// (SQ_LDS_BANK_CONFLICT 9.4M -> 0, rounds 9/11/13/14/16).
static __device__ __forceinline__ int swz_idx(int r, int c) {
    const int u = r >> 1;
    const int s = (((r & 1) << 2) | c) ^ (u & 7);
    return (u << 6) + (s << 3);   // u*64 shorts + s*8 shorts
}
// Inverse: 16B-slot p -> (r,c). Verified: swz_idx(r,c)/8 == p round-trips.
static __device__ __forceinline__ void inv_swz(int p, int& r, int& c) {
    const int u = p >> 3;
    const int bits = (p & 7) ^ (u & 7);
    r = (u << 1) | (bits >> 2);
    c = bits & 3;
}

// Async global->LDS 16B copy: per-lane global src, wave-uniform LDS base (+lane*16 by HW).
#define GLDS(gsrc, ldst)                                                          \
    __builtin_amdgcn_global_load_lds(                                             \
        (const __attribute__((address_space(1))) uint32_t*)(gsrc),                \
        (__attribute__((address_space(3))) uint32_t*)(ldst), 16, 0, 0)

static __device__ __forceinline__ int cantor_m(int t) {
    float x = (float)t / (float)(TT - 1);
    x = fminf(fmaxf(x, 1e-6f), 1.0f - 1e-6f);
    int m = 0;
    #pragma unroll
    for (int i = 0; i < CDEPTH; ++i) {
        float x3 = x * 3.0f;
        float dg = floorf(x3);
        x = x3 - dg;
        m = (m << 1) | ((dg == 2.0f) ? 1 : 0);
    }
    return m;
}

// ---------------- Routes kernel A: per-bucket first-16 + counts (256 blocks) ----------------
__global__ __launch_bounds__(256) void routes_f16_kernel(int* __restrict__ kv_g,
                                                         int* __restrict__ cnt_g,
                                                         int* __restrict__ f16_g) {
    __shared__ int kvloc[TT];
    __shared__ int pscan[256];
    const int tid = threadIdx.x;
    const int b = blockIdx.x;

    #pragma unroll
    for (int i = 0; i < 16; ++i) {
        const int t = i * 256 + tid;
        kvloc[t] = cantor_m(t);
    }
    __syncthreads();

    if (tid < 16) kv_g[b * 16 + tid] = kvloc[b * 16 + tid];

    int localcnt = 0;
    #pragma unroll
    for (int i = 0; i < 16; ++i)
        localcnt += (kvloc[tid * 16 + i] == b) ? 1 : 0;

    pscan[tid] = localcnt;
    __syncthreads();
    #pragma unroll
    for (int off = 1; off < 256; off <<= 1) {
        int v = (tid >= off) ? pscan[tid - off] : 0;
        __syncthreads();
        pscan[tid] += v;
        __syncthreads();
    }
    const int excl = pscan[tid] - localcnt;

    int r = excl;
    #pragma unroll
    for (int i = 0; i < 16; ++i) {
        const int t = tid * 16 + i;
        if (kvloc[t] == b) {
            if (r < 16) f16_g[b * 16 + r] = t;
            ++r;
        }
    }
    if (tid == 255) cnt_g[b] = pscan[255];
}

// ---------------- Routes kernel B: ring-merge selection per bucket (1 block) ----------------
__global__ __launch_bounds__(256) void routes_merge_kernel(const int* __restrict__ cnt_g,
                                                           const int* __restrict__ f16_g,
                                                           int* __restrict__ table) {
    __shared__ int cnt[256];
    __shared__ int f16[256][16];
    const int tid = threadIdx.x;
    cnt[tid] = cnt_g[tid];
    {
        int4 a = reinterpret_cast<const int4*>(f16_g)[tid * 4 + 0];
        int4 b4 = reinterpret_cast<const int4*>(f16_g)[tid * 4 + 1];
        int4 c4 = reinterpret_cast<const int4*>(f16_g)[tid * 4 + 2];
        int4 d4 = reinterpret_cast<const int4*>(f16_g)[tid * 4 + 3];
        f16[tid][0] = a.x;  f16[tid][1] = a.y;  f16[tid][2] = a.z;  f16[tid][3] = a.w;
        f16[tid][4] = b4.x; f16[tid][5] = b4.y; f16[tid][6] = b4.z; f16[tid][7] = b4.w;
        f16[tid][8] = c4.x; f16[tid][9] = c4.y; f16[tid][10] = c4.z; f16[tid][11] = c4.w;
        f16[tid][12] = d4.x; f16[tid][13] = d4.y; f16[tid][14] = d4.z; f16[tid][15] = d4.w;
    }
    __syncthreads();

    int rtl[WW];
    int n = 0;
    {
        int c = cnt[tid];
        int take = (c < WW) ? c : WW;
        for (int i = 0; i < take; ++i) rtl[n++] = f16[tid][i];
    }
    for (int d = 1; n < WW && d <= 256; ++d) {
        const int lo = tid - d, hi = tid + d;
        const int clo = (lo >= 0) ? cnt[lo] : 0;
        const int chi = (hi < 256) ? cnt[hi] : 0;
        const int need = WW - n;
        if (clo + chi <= need) {
            for (int i = 0; i < clo; ++i) rtl[n++] = f16[lo][i];
            for (int i = 0; i < chi; ++i) rtl[n++] = f16[hi][i];
        } else {
            const int cl = (clo < WW) ? clo : WW;
            const int ch = (chi < WW) ? chi : WW;
            int i = 0, j = 0;
            while (n < WW) {
                int a = (i < cl) ? f16[lo][i] : INT_MAX;
                int b = (j < ch) ? f16[hi][j] : INT_MAX;
                if (a < b) { rtl[n++] = a; ++i; }
                else       { rtl[n++] = b; ++j; }
            }
        }
    }
    #pragma unroll
    for (int i = 0; i < WW; ++i) table[tid * WW + i] = rtl[i];
}

// ---------------- W[k][n] -> pre-swizzled bf16 hi/lo tiles ----------------
// Layout per weight: [nt 0..3][kt 0..15][slot 0..511] of 16B chunks (slot = swz_idx/8).
__global__ __launch_bounds__(256) void convw_tile_kernel(
        const float* __restrict__ W0, const float* __restrict__ W1,
        const float* __restrict__ W2, const float* __restrict__ W3,
        ushortT* __restrict__ H0, ushortT* __restrict__ L0,
        ushortT* __restrict__ H1, ushortT* __restrict__ L1,
        ushortT* __restrict__ H2, ushortT* __restrict__ L2,
        ushortT* __restrict__ H3, ushortT* __restrict__ L3) {
    const float* src; ushortT* dh; ushortT* dl;
    switch (blockIdx.z) {
        case 0: src = W0; dh = H0; dl = L0; break;
        case 1: src = W1; dh = H1; dl = L1; break;
        case 2: src = W2; dh = H2; dl = L2; break;
        default: src = W3; dh = H3; dl = L3; break;
    }
    const int nt = blockIdx.x;           // 0..3
    const int kt = blockIdx.y;           // 0..15
    const size_t tilebase = ((size_t)(nt * 16 + kt)) * 4096;  // shorts (512 slots * 8)

    #pragma unroll
    for (int s = 0; s < 2; ++s) {
        const int p = threadIdx.x + s * 256;   // slot 0..511
        int r, c;
        inv_swz(p, r, c);
        const int n = nt * 128 + r;
        const int k = kt * 32 + c * 8;
        uintT rh[8], rl[8];
        #pragma unroll
        for (int j = 0; j < 8; ++j) {
            const float f = src[(size_t)(k + j) * DD + n];
            const uintT h = f2bf(f);
            rh[j] = h;
            rl[j] = f2bf(f - bf2f(h));
        }
        uint4 oh, ol;
        oh.x = rh[0] | (rh[1] << 16); oh.y = rh[2] | (rh[3] << 16);
        oh.z = rh[4] | (rh[5] << 16); oh.w = rh[6] | (rh[7] << 16);
        ol.x = rl[0] | (rl[1] << 16); ol.y = rl[2] | (rl[3] << 16);
        ol.z = rl[4] | (rl[5] << 16); ol.w = rl[6] | (rl[7] << 16);
        *reinterpret_cast<uint4*>(&dh[tilebase + (size_t)p * 8]) = oh;
        *reinterpret_cast<uint4*>(&dl[tilebase + (size_t)p * 8]) = ol;
    }
}

// ---------------- Fused QKV GEMM: 64x128 tile, BK=32, split-bf16 3-term, 2-PHASE ----------------
// Double-buffered LDS, ONE barrier per K-step: STAGE(buf^1, t+1) issued before
// COMPUTE(buf, t) so staged-load latency hides under the 24 MFMAs (T3 minimum
// 2-phase; staging bodies identical to the verified 1-phase version).
#define QBM 64
#define QBN 128
#define QBK 32
#define ASZ (QBM * QBK)   // 2048 shorts
#define BSZ (QBN * QBK)   // 4096 shorts
#define QKV_NWG 1536
#define OUT_NWG 512

#define STAGE_QKV(bufIdx, kt_)                                                    \
    {                                                                             \
        const int boff = (bufIdx) * BSZ;                                          \
        const size_t tb = ((size_t)(nt * 16 + (kt_))) * 4096;                     \
        const int base = wid * 128;                                               \
        _Pragma("unroll")                                                         \
        for (int q = 0; q < 2; ++q) {                                             \
            const size_t so = tb + (size_t)(base + q * 64 + lane) * 8;            \
            GLDS(&Bhp[so], &Bsh[boff + (base + q * 64) * 8]);                     \
            GLDS(&Blp[so], &Bsl[boff + (base + q * 64) * 8]);                     \
        }                                                                         \
        const float* srcp = &x[(size_t)(bm + arow) * DD + (kt_) * 32 + achk * 8]; \
        const float4 v0 = *reinterpret_cast<const float4*>(srcp);                 \
        const float4 v1 = *reinterpret_cast<const float4*>(srcp + 4);             \
        const float vv[8] = {v0.x, v0.y, v0.z, v0.w, v1.x, v1.y, v1.z, v1.w};     \
        bf16x8 vh, vl;                                                            \
        _Pragma("unroll")                                                         \
        for (int j = 0; j < 8; ++j) {                                             \
            uintT h = f2bf(vv[j]);                                                \
            vh[j] = (short)h;                                                     \
            vl[j] = (short)f2bf(vv[j] - bf2f(h));                                 \
        }                                                                         \
        const int ai = (bufIdx) * ASZ + swz_idx(arow, achk);                      \
        *reinterpret_cast<bf16x8*>(&Ash[ai]) = vh;                                \
        *reinterpret_cast<bf16x8*>(&Asl[ai]) = vl;                                \
    }

#define COMPUTE_QKV(bufIdx)                                                       \
    {                                                                             \
        const int aoff = (bufIdx) * ASZ;                                          \
        const int boff = (bufIdx) * BSZ;                                          \
        bf16x8 avh[2], avl[2], bvh[4], bvl[4];                                    \
        _Pragma("unroll")                                                         \
        for (int i = 0; i < 2; ++i) {                                             \
            const int ai = aoff + swz_idx(wr * 32 + i * 16 + fr, kq);             \
            avh[i] = *reinterpret_cast<const bf16x8*>(&Ash[ai]);                  \
            avl[i] = *reinterpret_cast<const bf16x8*>(&Asl[ai]);                  \
        }                                                                         \
        _Pragma("unroll")                                                         \
        for (int j = 0; j < 4; ++j) {                                             \
            const int bi = boff + swz_idx(wc * 64 + j * 16 + fr, kq);             \
            bvh[j] = *reinterpret_cast<const bf16x8*>(&Bsh[bi]);                  \
            bvl[j] = *reinterpret_cast<const bf16x8*>(&Bsl[bi]);                  \
        }                                                                         \
        _Pragma("unroll")                                                         \
        for (int i = 0; i < 2; ++i)                                               \
            _Pragma("unroll")                                                     \
            for (int j = 0; j < 4; ++j) {                                         \
                acc[i][j] = __builtin_amdgcn_mfma_f32_16x16x32_bf16(avh[i], bvh[j], acc[i][j], 0, 0, 0); \
                acc[i][j] = __builtin_amdgcn_mfma_f32_16x16x32_bf16(avl[i], bvh[j], acc[i][j], 0, 0, 0); \
                acc[i][j] = __builtin_amdgcn_mfma_f32_16x16x32_bf16(avh[i], bvl[j], acc[i][j], 0, 0, 0); \
            }                                                                     \
    }

__global__ __launch_bounds__(256, 3) void qkv_gemm(const float* __restrict__ x,
        const ushortT* __restrict__ Wqh, const ushortT* __restrict__ Wql,
        const ushortT* __restrict__ Wkh, const ushortT* __restrict__ Wkl,
        const ushortT* __restrict__ Wvh, const ushortT* __restrict__ Wvl,
        const float* __restrict__ bq, const float* __restrict__ bk, const float* __restrict__ bv,
        float* __restrict__ Qo, float* __restrict__ Ko, ushortT* __restrict__ Vo, int M) {
    __shared__ short Ash[2 * ASZ];          // 2 x 4 KB, swizzled
    __shared__ short Asl[2 * ASZ];
    __shared__ short Bsh[2 * BSZ];          // 2 x 8 KB, swizzled (slot-linear from W')
    __shared__ short Bsl[2 * BSZ];
    const int tid = threadIdx.x;
    const int lane = tid & 63;
    const int wid = tid >> 6;

    // T1 bijective XCD swizzle (nwg % 8 == 0): same-XCD blocks share bm-range.
    const int id = blockIdx.x;
    const int swz = (id & 7) * (QKV_NWG / 8) + (id >> 3);
    const int bm = (swz / 12) * QBM;
    const int bnG = (swz % 12) * QBN;       // 0..1535
    const int seg = bnG >> 9;               // 0=Q 1=K 2=V
    const int bn = bnG & 511;
    const ushortT* __restrict__ Bhp = (seg == 0) ? Wqh : (seg == 1) ? Wkh : Wvh;
    const ushortT* __restrict__ Blp = (seg == 0) ? Wql : (seg == 1) ? Wkl : Wvl;
    const float* __restrict__ bias = (seg == 0) ? bq : (seg == 1) ? bk : bv;

    const int wr = wid >> 1;                // 0..1 : 32-row slab
    const int wc = wid & 1;                 // 0..1 : 64-col slab

    f32x4 acc[2][4];
    #pragma unroll
    for (int i = 0; i < 2; ++i)
        #pragma unroll
        for (int j = 0; j < 4; ++j)
            acc[i][j] = (f32x4){0.f, 0.f, 0.f, 0.f};

    const int arow = tid >> 2;              // 0..63
    const int achk = tid & 3;               // 16B chunk
    const int fr = lane & 15;
    const int kq = lane >> 4;               // fragment 16B chunk
    const int nt = bn >> 7;                 // W' tile column index

    // Prologue: stage k-tile 0 into buffer 0
    STAGE_QKV(0, 0)
    __syncthreads();

    int cur = 0;
    #pragma unroll 1
    for (int t = 0; t < 15; ++t) {
        STAGE_QKV(cur ^ 1, t + 1)           // prefetch next tile (hides under MFMA)
        COMPUTE_QKV(cur)
        __syncthreads();                    // one barrier per K-step
        cur ^= 1;
    }
    COMPUTE_QKV(cur)                        // epilogue tile (t=15)

    const int fq = lane >> 4;
    #pragma unroll
    for (int j = 0; j < 4; ++j) {
        const int col = bn + wc * 64 + j * 16 + fr;
        const float bvv = bias[col];
        #pragma unroll
        for (int i = 0; i < 2; ++i) {
            const int row0 = bm + wr * 32 + i * 16 + fq * 4;
            #pragma unroll
            for (int r = 0; r < 4; ++r) {
                const float val = acc[i][j][r] + bvv;
                if (seg == 2) {
                    Vo[(size_t)(row0 + r) * DD + col] = (ushortT)f2bf(val);
                } else {
                    float* dst = seg ? Ko : Qo;
                    dst[(size_t)(row0 + r) * DD + col] = val;
                }
            }
        }
    }
}

// ---------------- Output GEMM: A = AO hi/lo bf16 (reg-staged), B = Wo pre-swizzled ----------------
__global__ __launch_bounds__(256, 6) void out_gemm(const ushortT* __restrict__ Ahg,
                                                   const ushortT* __restrict__ Alg,
                                                   const ushortT* __restrict__ Bh,
                                                   const ushortT* __restrict__ Bl,
                                                   const float* __restrict__ bias,
                                                   float* __restrict__ C, int M) {
    __shared__ short Ash[QBM * QBK];
    __shared__ short Asl[QBM * QBK];
    __shared__ short Bsh[QBN * QBK];
    __shared__ short Bsl[QBN * QBK];
    const int tid = threadIdx.x;
    const int lane = tid & 63;
    const int wid = tid >> 6;

    const int id = blockIdx.x;
    const int swz = (id & 7) * (OUT_NWG / 8) + (id >> 3);
    const int bm = (swz >> 2) * QBM;
    const int bn = (swz & 3) * QBN;
    const int wr = wid >> 1;
    const int wc = wid & 1;

    f32x4 acc[2][4];
    #pragma unroll
    for (int i = 0; i < 2; ++i)
        #pragma unroll
        for (int j = 0; j < 4; ++j)
            acc[i][j] = (f32x4){0.f, 0.f, 0.f, 0.f};

    const int arow = tid >> 2;
    const int achk = tid & 3;
    const int fr = lane & 15;
    const int kq = lane >> 4;
    const int nt = bn >> 7;

    for (int k0 = 0; k0 < DD; k0 += QBK) {
        // B staging: async identity copy of pre-swizzled Wo tile
        {
            const size_t tb = ((size_t)(nt * 16 + (k0 >> 5))) * 4096;
            const int base = wid * 128;
            #pragma unroll
            for (int q = 0; q < 2; ++q) {
                const size_t so = tb + (size_t)(base + q * 64 + lane) * 8;
                GLDS(&Bh[so], &Bsh[(base + q * 64) * 8]);
                GLDS(&Bl[so], &Bsl[(base + q * 64) * 8]);
            }
        }
        // A staging: reg path (linear rows), swizzled ds_write
        {
            const size_t g = (size_t)(bm + arow) * DD + k0 + achk * 8;
            const int ai = swz_idx(arow, achk);
            *reinterpret_cast<bf16x8*>(&Ash[ai]) = *reinterpret_cast<const bf16x8*>(&Ahg[g]);
            *reinterpret_cast<bf16x8*>(&Asl[ai]) = *reinterpret_cast<const bf16x8*>(&Alg[g]);
        }
        __syncthreads();
        {
            bf16x8 avh[2], avl[2], bvh[4], bvl[4];
            #pragma unroll
            for (int i = 0; i < 2; ++i) {
                const int ai = swz_idx(wr * 32 + i * 16 + fr, kq);
                avh[i] = *reinterpret_cast<const bf16x8*>(&Ash[ai]);
                avl[i] = *reinterpret_cast<const bf16x8*>(&Asl[ai]);
            }
            #pragma unroll
            for (int j = 0; j < 4; ++j) {
                const int bi = swz_idx(wc * 64 + j * 16 + fr, kq);
                bvh[j] = *reinterpret_cast<const bf16x8*>(&Bsh[bi]);
                bvl[j] = *reinterpret_cast<const bf16x8*>(&Bsl[bi]);
            }
            #pragma unroll
            for (int i = 0; i < 2; ++i)
                #pragma unroll
                for (int j = 0; j < 4; ++j) {
                    acc[i][j] = __builtin_amdgcn_mfma_f32_16x16x32_bf16(avh[i], bvh[j], acc[i][j], 0, 0, 0);
                    acc[i][j] = __builtin_amdgcn_mfma_f32_16x16x32_bf16(avl[i], bvh[j], acc[i][j], 0, 0, 0);
                    acc[i][j] = __builtin_amdgcn_mfma_f32_16x16x32_bf16(avh[i], bvl[j], acc[i][j], 0, 0, 0);
                }
        }
        __syncthreads();
    }

    const int fq = lane >> 4;
    #pragma unroll
    for (int j = 0; j < 4; ++j) {
        const int col = bn + wc * 64 + j * 16 + fr;
        const float bvv = bias[col];
        #pragma unroll
        for (int i = 0; i < 2; ++i) {
            const int row0 = bm + wr * 32 + i * 16 + fq * 4;
            #pragma unroll
            for (int r = 0; r < 4; ++r)
                C[(size_t)(row0 + r) * DD + col] = acc[i][j][r] + bvv;
        }
    }
}

// ---------------- Attention: one wave per (b,t), all 8 heads; V bf16; AO hi/lo ----------------
__global__ __launch_bounds__(256) void attn2_kernel(const float* __restrict__ Q,
                                                    const float* __restrict__ K,
                                                    const ushortT* __restrict__ V,
                                                    const int* __restrict__ kv_g,
                                                    const int* __restrict__ table,
                                                    const float* __restrict__ temp_ptr,
                                                    ushortT* __restrict__ AOh,
                                                    ushortT* __restrict__ AOl, int B) {
    const int lane = threadIdx.x & 63;
    const int u = (blockIdx.x * blockDim.x + threadIdx.x) >> 6;  // b*TT + t
    if (u >= B * TT) return;
    const int t = u & (TT - 1);
    const float scale_inv = 1.0f / (8.0f * fabsf(temp_ptr[0]));

    const int* rt = &table[kv_g[t] * WW];
    int sidx[WW];
    #pragma unroll
    for (int w = 0; w < WW; ++w) sidx[w] = rt[w];

    const size_t rowbase = (size_t)u * DD + lane * 8;
    const size_t bbase = (size_t)(u - t) * DD;
    const float4 q0 = *reinterpret_cast<const float4*>(&Q[rowbase]);
    const float4 q1 = *reinterpret_cast<const float4*>(&Q[rowbase + 4]);

    float sc[WW];
    #pragma unroll
    for (int w = 0; w < WW; ++w) {
        const float* kr = &K[bbase + (size_t)sidx[w] * DD + lane * 8];
        const float4 k0 = *reinterpret_cast<const float4*>(kr);
        const float4 k1 = *reinterpret_cast<const float4*>(kr + 4);
        float p = q0.x * k0.x + q0.y * k0.y + q0.z * k0.z + q0.w * k0.w
                + q1.x * k1.x + q1.y * k1.y + q1.z * k1.z + q1.w * k1.w;
        p += __shfl_xor(p, 1);
        p += __shfl_xor(p, 2);
        p += __shfl_xor(p, 4);
        sc[w] = p * scale_inv;
    }

    float m = sc[0];
    #pragma unroll
    for (int w = 1; w < WW; ++w) m = fmaxf(m, sc[w]);
    float pr[WW];
    float sum = 0.0f;
    #pragma unroll
    for (int w = 0; w < WW; ++w) { pr[w] = expf(sc[w] - m); sum += pr[w]; }
    const float inv = 1.0f / sum;

    float o[8] = {0.f, 0.f, 0.f, 0.f, 0.f, 0.f, 0.f, 0.f};
    #pragma unroll
    for (int w = 0; w < WW; ++w) {
        const uint4 vv = *reinterpret_cast<const uint4*>(&V[bbase + (size_t)sidx[w] * DD + lane * 8]);
        o[0] += pr[w] * bf2f(vv.x & 0xffffu); o[1] += pr[w] * bf2f(vv.x >> 16);
        o[2] += pr[w] * bf2f(vv.y & 0xffffu); o[3] += pr[w] * bf2f(vv.y >> 16);
        o[4] += pr[w] * bf2f(vv.z & 0xffffu); o[5] += pr[w] * bf2f(vv.z >> 16);
        o[6] += pr[w] * bf2f(vv.w & 0xffffu); o[7] += pr[w] * bf2f(vv.w >> 16);
    }
    uintT rh[8], rl[8];
    #pragma unroll
    for (int i = 0; i < 8; ++i) {
        const float val = o[i] * inv;
        uintT h = f2bf(val);
        rh[i] = h;
        rl[i] = f2bf(val - bf2f(h));
    }
    uint4 oh, ol;
    oh.x = rh[0] | (rh[1] << 16); oh.y = rh[2] | (rh[3] << 16);
    oh.z = rh[4] | (rh[5] << 16); oh.w = rh[6] | (rh[7] << 16);
    ol.x = rl[0] | (rl[1] << 16); ol.y = rl[2] | (rl[3] << 16);
    ol.z = rl[4] | (rl[5] << 16); ol.w = rl[6] | (rl[7] << 16);
    *reinterpret_cast<uint4*>(&AOh[rowbase]) = oh;
    *reinterpret_cast<uint4*>(&AOl[rowbase]) = ol;
}

// ---------------- Launcher ----------------
extern "C" void kernel_launch(void* const* d_in, const int* in_sizes, int n_in,
                              void* d_out, int out_size, void* d_ws, size_t ws_size,
                              hipStream_t stream) {
    const float* x    = (const float*)d_in[0];
    const float* Wq   = (const float*)d_in[1];
    const float* bq   = (const float*)d_in[2];
    const float* Wk   = (const float*)d_in[3];
    const float* bk   = (const float*)d_in[4];
    const float* Wv   = (const float*)d_in[5];
    const float* bv   = (const float*)d_in[6];
    const float* Wo   = (const float*)d_in[7];
    const float* bo   = (const float*)d_in[8];
    const float* temp = (const float*)d_in[9];
    float* out = (float*)d_out;

    const int B = in_sizes[0] / (TT * DD);   // 2
    const int M = B * TT;                    // 8192
    const size_t MD = (size_t)M * DD;

    float* Qb = (float*)d_ws;                          // fp32
    float* Kb = Qb + MD;                               // fp32
    ushortT* Vb = (ushortT*)(Kb + MD);                 // bf16
    ushortT* AOh = Vb + MD;
    ushortT* AOl = AOh + MD;
    ushortT* Wqh = AOl + MD;
    ushortT* Wql = Wqh + DD * DD;
    ushortT* Wkh = Wql + DD * DD;
    ushortT* Wkl = Wkh + DD * DD;
    ushortT* Wvh = Wkl + DD * DD;
    ushortT* Wvl = Wvh + DD * DD;
    ushortT* Woh = Wvl + DD * DD;
    ushortT* Wol = Woh + DD * DD;
    int* kvg   = (int*)(Wol + DD * DD);
    int* table = kvg + TT;
    int* cntg  = table + 256 * WW;
    int* f16g  = cntg + 256;

    routes_f16_kernel<<<256, 256, 0, stream>>>(kvg, cntg, f16g);
    routes_merge_kernel<<<1, 256, 0, stream>>>(cntg, f16g, table);
    convw_tile_kernel<<<dim3(4, 16, 4), 256, 0, stream>>>(Wq, Wk, Wv, Wo,
                                                          Wqh, Wql, Wkh, Wkl,
                                                          Wvh, Wvl, Woh, Wol);

    qkv_gemm<<<QKV_NWG, 256, 0, stream>>>(x, Wqh, Wql, Wkh, Wkl, Wvh, Wvl,
                                          bq, bk, bv, Qb, Kb, Vb, M);

    attn2_kernel<<<(M * 64) / 256, 256, 0, stream>>>(Qb, Kb, Vb, kvg, table, temp, AOh, AOl, B);

    out_gemm<<<OUT_NWG, 256, 0, stream>>>(AOh, AOl, Woh, Wol, bo, out, M);
}

// Round 19
// 142.540 us; speedup vs baseline: 1.0351x; 1.0351x over previous
//
#include <hip/hip_runtime.h>
#include <hip/hip_bf16.h>
#include <cstdint>
#include <climits>

#define TT 4096
#define DD 512
#define HH 8
#define HD 64
#define WW 16
#define CDEPTH 8

typedef unsigned short ushortT;
typedef unsigned int uintT;
using bf16x8 = __attribute__((ext_vector_type(8))) short;
using f32x4  = __attribute__((ext_vector_type(4))) float;

static __device__ __forceinline__ uintT f2bf(float v) {
    __hip_bfloat16 h = __float2bfloat16(v);
    return (uintT)*reinterpret_cast<ushortT*>(&h);
}
static __device__ __forceinline__ float bf2f(uintT u) {
    return __uint_as_float(u << 16);
}

// Swizzled LDS index (in shorts) for [row][32 shorts] tiles merged as 128B super-rows.
// r = logical row, c = 16B-chunk index (0..3). Bijective; verified conflict-free
// (SQ_LDS_BANK_CONFLICT 9.4M -> 0, rounds 9/11/13/14/16).
static __device__ __forceinline__ int swz_idx(int r, int c) {
    const int u = r >> 1;
    const int s = (((r & 1) << 2) | c) ^ (u & 7);
    return (u << 6) + (s << 3);   // u*64 shorts + s*8 shorts
}
// Inverse: 16B-slot p -> (r,c). Verified: swz_idx(r,c)/8 == p round-trips.
static __device__ __forceinline__ void inv_swz(int p, int& r, int& c) {
    const int u = p >> 3;
    const int bits = (p & 7) ^ (u & 7);
    r = (u << 1) | (bits >> 2);
    c = bits & 3;
}

// Async global->LDS 16B copy: per-lane global src, wave-uniform LDS base (+lane*16 by HW).
#define GLDS(gsrc, ldst)                                                          \
    __builtin_amdgcn_global_load_lds(                                             \
        (const __attribute__((address_space(1))) uint32_t*)(gsrc),                \
        (__attribute__((address_space(3))) uint32_t*)(ldst), 16, 0, 0)

static __device__ __forceinline__ int cantor_m(int t) {
    float x = (float)t / (float)(TT - 1);
    x = fminf(fmaxf(x, 1e-6f), 1.0f - 1e-6f);
    int m = 0;
    #pragma unroll
    for (int i = 0; i < CDEPTH; ++i) {
        float x3 = x * 3.0f;
        float dg = floorf(x3);
        x = x3 - dg;
        m = (m << 1) | ((dg == 2.0f) ? 1 : 0);
    }
    return m;
}

// ---------------- Routes kernel A: per-bucket first-16 + counts (256 blocks) ----------------
__global__ __launch_bounds__(256) void routes_f16_kernel(int* __restrict__ kv_g,
                                                         int* __restrict__ cnt_g,
                                                         int* __restrict__ f16_g) {
    __shared__ int kvloc[TT];
    __shared__ int pscan[256];
    const int tid = threadIdx.x;
    const int b = blockIdx.x;

    #pragma unroll
    for (int i = 0; i < 16; ++i) {
        const int t = i * 256 + tid;
        kvloc[t] = cantor_m(t);
    }
    __syncthreads();

    if (tid < 16) kv_g[b * 16 + tid] = kvloc[b * 16 + tid];

    int localcnt = 0;
    #pragma unroll
    for (int i = 0; i < 16; ++i)
        localcnt += (kvloc[tid * 16 + i] == b) ? 1 : 0;

    pscan[tid] = localcnt;
    __syncthreads();
    #pragma unroll
    for (int off = 1; off < 256; off <<= 1) {
        int v = (tid >= off) ? pscan[tid - off] : 0;
        __syncthreads();
        pscan[tid] += v;
        __syncthreads();
    }
    const int excl = pscan[tid] - localcnt;

    int r = excl;
    #pragma unroll
    for (int i = 0; i < 16; ++i) {
        const int t = tid * 16 + i;
        if (kvloc[t] == b) {
            if (r < 16) f16_g[b * 16 + r] = t;
            ++r;
        }
    }
    if (tid == 255) cnt_g[b] = pscan[255];
}

// ---------------- Routes kernel B: ring-merge selection per bucket (1 block) ----------------
__global__ __launch_bounds__(256) void routes_merge_kernel(const int* __restrict__ cnt_g,
                                                           const int* __restrict__ f16_g,
                                                           int* __restrict__ table) {
    __shared__ int cnt[256];
    __shared__ int f16[256][16];
    const int tid = threadIdx.x;
    cnt[tid] = cnt_g[tid];
    {
        int4 a = reinterpret_cast<const int4*>(f16_g)[tid * 4 + 0];
        int4 b4 = reinterpret_cast<const int4*>(f16_g)[tid * 4 + 1];
        int4 c4 = reinterpret_cast<const int4*>(f16_g)[tid * 4 + 2];
        int4 d4 = reinterpret_cast<const int4*>(f16_g)[tid * 4 + 3];
        f16[tid][0] = a.x;  f16[tid][1] = a.y;  f16[tid][2] = a.z;  f16[tid][3] = a.w;
        f16[tid][4] = b4.x; f16[tid][5] = b4.y; f16[tid][6] = b4.z; f16[tid][7] = b4.w;
        f16[tid][8] = c4.x; f16[tid][9] = c4.y; f16[tid][10] = c4.z; f16[tid][11] = c4.w;
        f16[tid][12] = d4.x; f16[tid][13] = d4.y; f16[tid][14] = d4.z; f16[tid][15] = d4.w;
    }
    __syncthreads();

    int rtl[WW];
    int n = 0;
    {
        int c = cnt[tid];
        int take = (c < WW) ? c : WW;
        for (int i = 0; i < take; ++i) rtl[n++] = f16[tid][i];
    }
    for (int d = 1; n < WW && d <= 256; ++d) {
        const int lo = tid - d, hi = tid + d;
        const int clo = (lo >= 0) ? cnt[lo] : 0;
        const int chi = (hi < 256) ? cnt[hi] : 0;
        const int need = WW - n;
        if (clo + chi <= need) {
            for (int i = 0; i < clo; ++i) rtl[n++] = f16[lo][i];
            for (int i = 0; i < chi; ++i) rtl[n++] = f16[hi][i];
        } else {
            const int cl = (clo < WW) ? clo : WW;
            const int ch = (chi < WW) ? chi : WW;
            int i = 0, j = 0;
            while (n < WW) {
                int a = (i < cl) ? f16[lo][i] : INT_MAX;
                int b = (j < ch) ? f16[hi][j] : INT_MAX;
                if (a < b) { rtl[n++] = a; ++i; }
                else       { rtl[n++] = b; ++j; }
            }
        }
    }
    #pragma unroll
    for (int i = 0; i < WW; ++i) table[tid * WW + i] = rtl[i];
}

// ---------------- W[k][n] -> pre-swizzled bf16 hi/lo tiles ----------------
// Layout per weight: [nt 0..3][kt 0..15][slot 0..511] of 16B chunks, where slot
// index equals swz_idx(r,c)/8 for chunk (row r in tile, k-chunk c). This lets the
// GEMMs stage B with linear global_load_lds while keeping the swizzled reads.
__global__ __launch_bounds__(256) void convw_tile_kernel(
        const float* __restrict__ W0, const float* __restrict__ W1,
        const float* __restrict__ W2, const float* __restrict__ W3,
        ushortT* __restrict__ H0, ushortT* __restrict__ L0,
        ushortT* __restrict__ H1, ushortT* __restrict__ L1,
        ushortT* __restrict__ H2, ushortT* __restrict__ L2,
        ushortT* __restrict__ H3, ushortT* __restrict__ L3) {
    const float* src; ushortT* dh; ushortT* dl;
    switch (blockIdx.z) {
        case 0: src = W0; dh = H0; dl = L0; break;
        case 1: src = W1; dh = H1; dl = L1; break;
        case 2: src = W2; dh = H2; dl = L2; break;
        default: src = W3; dh = H3; dl = L3; break;
    }
    const int nt = blockIdx.x;           // 0..3
    const int kt = blockIdx.y;           // 0..15
    const size_t tilebase = ((size_t)(nt * 16 + kt)) * 4096;  // shorts (512 slots * 8)

    #pragma unroll
    for (int s = 0; s < 2; ++s) {
        const int p = threadIdx.x + s * 256;   // slot 0..511
        int r, c;
        inv_swz(p, r, c);
        const int n = nt * 128 + r;
        const int k = kt * 32 + c * 8;
        uintT rh[8], rl[8];
        #pragma unroll
        for (int j = 0; j < 8; ++j) {
            const float f = src[(size_t)(k + j) * DD + n];
            const uintT h = f2bf(f);
            rh[j] = h;
            rl[j] = f2bf(f - bf2f(h));
        }
        uint4 oh, ol;
        oh.x = rh[0] | (rh[1] << 16); oh.y = rh[2] | (rh[3] << 16);
        oh.z = rh[4] | (rh[5] << 16); oh.w = rh[6] | (rh[7] << 16);
        ol.x = rl[0] | (rl[1] << 16); ol.y = rl[2] | (rl[3] << 16);
        ol.z = rl[4] | (rl[5] << 16); ol.w = rl[6] | (rl[7] << 16);
        *reinterpret_cast<uint4*>(&dh[tilebase + (size_t)p * 8]) = oh;
        *reinterpret_cast<uint4*>(&dl[tilebase + (size_t)p * 8]) = ol;
    }
}

// ---------------- Fused QKV GEMM: 64x128 tile, BK=32, split-bf16 3-term ----------------
// B staged via global_load_lds from pre-swizzled W tiles (linear copy); A reg-staged
// with inline fp32->hi/lo split. XCD swizzle + LDS XOR-swizzle as verified.
// Best verified configuration: 142.8 us total (rounds 14/16).
#define QBM 64
#define QBN 128
#define QBK 32
#define QKV_NWG 1536
#define OUT_NWG 512

__global__ __launch_bounds__(256, 6) void qkv_gemm(const float* __restrict__ x,
        const ushortT* __restrict__ Wqh, const ushortT* __restrict__ Wql,
        const ushortT* __restrict__ Wkh, const ushortT* __restrict__ Wkl,
        const ushortT* __restrict__ Wvh, const ushortT* __restrict__ Wvl,
        const float* __restrict__ bq, const float* __restrict__ bk, const float* __restrict__ bv,
        float* __restrict__ Qo, float* __restrict__ Ko, ushortT* __restrict__ Vo, int M) {
    __shared__ short Ash[QBM * QBK];        // 4 KB, swizzled
    __shared__ short Asl[QBM * QBK];
    __shared__ short Bsh[QBN * QBK];        // 8 KB, swizzled (slot-linear from W')
    __shared__ short Bsl[QBN * QBK];
    const int tid = threadIdx.x;
    const int lane = tid & 63;
    const int wid = tid >> 6;

    // T1 bijective XCD swizzle (nwg % 8 == 0): same-XCD blocks share bm-range.
    const int id = blockIdx.x;
    const int swz = (id & 7) * (QKV_NWG / 8) + (id >> 3);
    const int bm = (swz / 12) * QBM;
    const int bnG = (swz % 12) * QBN;       // 0..1535
    const int seg = bnG >> 9;               // 0=Q 1=K 2=V
    const int bn = bnG & 511;
    const ushortT* __restrict__ Bhp = (seg == 0) ? Wqh : (seg == 1) ? Wkh : Wvh;
    const ushortT* __restrict__ Blp = (seg == 0) ? Wql : (seg == 1) ? Wkl : Wvl;
    const float* __restrict__ bias = (seg == 0) ? bq : (seg == 1) ? bk : bv;

    const int wr = wid >> 1;                // 0..1 : 32-row slab
    const int wc = wid & 1;                 // 0..1 : 64-col slab

    f32x4 acc[2][4];
    #pragma unroll
    for (int i = 0; i < 2; ++i)
        #pragma unroll
        for (int j = 0; j < 4; ++j)
            acc[i][j] = (f32x4){0.f, 0.f, 0.f, 0.f};

    const int arow = tid >> 2;              // 0..63
    const int achk = tid & 3;               // 16B chunk
    const int fr = lane & 15;
    const int kq = lane >> 4;               // fragment 16B chunk
    const int nt = bn >> 7;                 // W' tile column index

    for (int k0 = 0; k0 < DD; k0 += QBK) {
        // B staging: async identity copy of the pre-swizzled 8 KB tile (per buffer)
        {
            const size_t tb = ((size_t)(nt * 16 + (k0 >> 5))) * 4096;  // shorts
            const int base = wid * 128;     // 128 slots per wave
            #pragma unroll
            for (int q = 0; q < 2; ++q) {
                const size_t so = tb + (size_t)(base + q * 64 + lane) * 8;
                GLDS(&Bhp[so], &Bsh[(base + q * 64) * 8]);
                GLDS(&Blp[so], &Bsl[(base + q * 64) * 8]);
            }
        }
        // A staging: fp32 -> hi/lo bf16 (identical arithmetic), swizzled ds_write
        {
            const float* srcp = &x[(size_t)(bm + arow) * DD + k0 + achk * 8];
            const float4 v0 = *reinterpret_cast<const float4*>(srcp);
            const float4 v1 = *reinterpret_cast<const float4*>(srcp + 4);
            const float vv[8] = {v0.x, v0.y, v0.z, v0.w, v1.x, v1.y, v1.z, v1.w};
            bf16x8 vh, vl;
            #pragma unroll
            for (int j = 0; j < 8; ++j) {
                uintT h = f2bf(vv[j]);
                vh[j] = (short)h;
                vl[j] = (short)f2bf(vv[j] - bf2f(h));
            }
            const int ai = swz_idx(arow, achk);
            *reinterpret_cast<bf16x8*>(&Ash[ai]) = vh;
            *reinterpret_cast<bf16x8*>(&Asl[ai]) = vl;
        }
        __syncthreads();
        {
            bf16x8 avh[2], avl[2], bvh[4], bvl[4];
            #pragma unroll
            for (int i = 0; i < 2; ++i) {
                const int ai = swz_idx(wr * 32 + i * 16 + fr, kq);
                avh[i] = *reinterpret_cast<const bf16x8*>(&Ash[ai]);
                avl[i] = *reinterpret_cast<const bf16x8*>(&Asl[ai]);
            }
            #pragma unroll
            for (int j = 0; j < 4; ++j) {
                const int bi = swz_idx(wc * 64 + j * 16 + fr, kq);
                bvh[j] = *reinterpret_cast<const bf16x8*>(&Bsh[bi]);
                bvl[j] = *reinterpret_cast<const bf16x8*>(&Bsl[bi]);
            }
            #pragma unroll
            for (int i = 0; i < 2; ++i)
                #pragma unroll
                for (int j = 0; j < 4; ++j) {
                    acc[i][j] = __builtin_amdgcn_mfma_f32_16x16x32_bf16(avh[i], bvh[j], acc[i][j], 0, 0, 0);
                    acc[i][j] = __builtin_amdgcn_mfma_f32_16x16x32_bf16(avl[i], bvh[j], acc[i][j], 0, 0, 0);
                    acc[i][j] = __builtin_amdgcn_mfma_f32_16x16x32_bf16(avh[i], bvl[j], acc[i][j], 0, 0, 0);
                }
        }
        __syncthreads();
    }

    const int fq = lane >> 4;
    #pragma unroll
    for (int j = 0; j < 4; ++j) {
        const int col = bn + wc * 64 + j * 16 + fr;
        const float bvv = bias[col];
        #pragma unroll
        for (int i = 0; i < 2; ++i) {
            const int row0 = bm + wr * 32 + i * 16 + fq * 4;
            #pragma unroll
            for (int r = 0; r < 4; ++r) {
                const float val = acc[i][j][r] + bvv;
                if (seg == 2) {
                    Vo[(size_t)(row0 + r) * DD + col] = (ushortT)f2bf(val);
                } else {
                    float* dst = seg ? Ko : Qo;
                    dst[(size_t)(row0 + r) * DD + col] = val;
                }
            }
        }
    }
}

// ---------------- Output GEMM: A = AO hi/lo bf16 (reg-staged), B = Wo pre-swizzled ----------------
__global__ __launch_bounds__(256, 6) void out_gemm(const ushortT* __restrict__ Ahg,
                                                   const ushortT* __restrict__ Alg,
                                                   const ushortT* __restrict__ Bh,
                                                   const ushortT* __restrict__ Bl,
                                                   const float* __restrict__ bias,
                                                   float* __restrict__ C, int M) {
    __shared__ short Ash[QBM * QBK];
    __shared__ short Asl[QBM * QBK];
    __shared__ short Bsh[QBN * QBK];
    __shared__ short Bsl[QBN * QBK];
    const int tid = threadIdx.x;
    const int lane = tid & 63;
    const int wid = tid >> 6;

    const int id = blockIdx.x;
    const int swz = (id & 7) * (OUT_NWG / 8) + (id >> 3);
    const int bm = (swz >> 2) * QBM;
    const int bn = (swz & 3) * QBN;
    const int wr = wid >> 1;
    const int wc = wid & 1;

    f32x4 acc[2][4];
    #pragma unroll
    for (int i = 0; i < 2; ++i)
        #pragma unroll
        for (int j = 0; j < 4; ++j)
            acc[i][j] = (f32x4){0.f, 0.f, 0.f, 0.f};

    const int arow = tid >> 2;
    const int achk = tid & 3;
    const int fr = lane & 15;
    const int kq = lane >> 4;
    const int nt = bn >> 7;

    for (int k0 = 0; k0 < DD; k0 += QBK) {
        // B staging: async identity copy of pre-swizzled Wo tile
        {
            const size_t tb = ((size_t)(nt * 16 + (k0 >> 5))) * 4096;
            const int base = wid * 128;
            #pragma unroll
            for (int q = 0; q < 2; ++q) {
                const size_t so = tb + (size_t)(base + q * 64 + lane) * 8;
                GLDS(&Bh[so], &Bsh[(base + q * 64) * 8]);
                GLDS(&Bl[so], &Bsl[(base + q * 64) * 8]);
            }
        }
        // A staging: reg path (linear rows), swizzled ds_write
        {
            const size_t g = (size_t)(bm + arow) * DD + k0 + achk * 8;
            const int ai = swz_idx(arow, achk);
            *reinterpret_cast<bf16x8*>(&Ash[ai]) = *reinterpret_cast<const bf16x8*>(&Ahg[g]);
            *reinterpret_cast<bf16x8*>(&Asl[ai]) = *reinterpret_cast<const bf16x8*>(&Alg[g]);
        }
        __syncthreads();
        {
            bf16x8 avh[2], avl[2], bvh[4], bvl[4];
            #pragma unroll
            for (int i = 0; i < 2; ++i) {
                const int ai = swz_idx(wr * 32 + i * 16 + fr, kq);
                avh[i] = *reinterpret_cast<const bf16x8*>(&Ash[ai]);
                avl[i] = *reinterpret_cast<const bf16x8*>(&Asl[ai]);
            }
            #pragma unroll
            for (int j = 0; j < 4; ++j) {
                const int bi = swz_idx(wc * 64 + j * 16 + fr, kq);
                bvh[j] = *reinterpret_cast<const bf16x8*>(&Bsh[bi]);
                bvl[j] = *reinterpret_cast<const bf16x8*>(&Bsl[bi]);
            }
            #pragma unroll
            for (int i = 0; i < 2; ++i)
                #pragma unroll
                for (int j = 0; j < 4; ++j) {
                    acc[i][j] = __builtin_amdgcn_mfma_f32_16x16x32_bf16(avh[i], bvh[j], acc[i][j], 0, 0, 0);
                    acc[i][j] = __builtin_amdgcn_mfma_f32_16x16x32_bf16(avl[i], bvh[j], acc[i][j], 0, 0, 0);
                    acc[i][j] = __builtin_amdgcn_mfma_f32_16x16x32_bf16(avh[i], bvl[j], acc[i][j], 0, 0, 0);
                }
        }
        __syncthreads();
    }

    const int fq = lane >> 4;
    #pragma unroll
    for (int j = 0; j < 4; ++j) {
        const int col = bn + wc * 64 + j * 16 + fr;
        const float bvv = bias[col];
        #pragma unroll
        for (int i = 0; i < 2; ++i) {
            const int row0 = bm + wr * 32 + i * 16 + fq * 4;
            #pragma unroll
            for (int r = 0; r < 4; ++r)
                C[(size_t)(row0 + r) * DD + col] = acc[i][j][r] + bvv;
        }
    }
}

// ---------------- Attention: one wave per (b,t), all 8 heads; V bf16; AO hi/lo ----------------
__global__ __launch_bounds__(256) void attn2_kernel(const float* __restrict__ Q,
                                                    const float* __restrict__ K,
                                                    const ushortT* __restrict__ V,
                                                    const int* __restrict__ kv_g,
                                                    const int* __restrict__ table,
                                                    const float* __restrict__ temp_ptr,
                                                    ushortT* __restrict__ AOh,
                                                    ushortT* __restrict__ AOl, int B) {
    const int lane = threadIdx.x & 63;
    const int u = (blockIdx.x * blockDim.x + threadIdx.x) >> 6;  // b*TT + t
    if (u >= B * TT) return;
    const int t = u & (TT - 1);
    const float scale_inv = 1.0f / (8.0f * fabsf(temp_ptr[0]));

    const int* rt = &table[kv_g[t] * WW];
    int sidx[WW];
    #pragma unroll
    for (int w = 0; w < WW; ++w) sidx[w] = rt[w];

    const size_t rowbase = (size_t)u * DD + lane * 8;
    const size_t bbase = (size_t)(u - t) * DD;
    const float4 q0 = *reinterpret_cast<const float4*>(&Q[rowbase]);
    const float4 q1 = *reinterpret_cast<const float4*>(&Q[rowbase + 4]);

    float sc[WW];
    #pragma unroll
    for (int w = 0; w < WW; ++w) {
        const float* kr = &K[bbase + (size_t)sidx[w] * DD + lane * 8];
        const float4 k0 = *reinterpret_cast<const float4*>(kr);
        const float4 k1 = *reinterpret_cast<const float4*>(kr + 4);
        float p = q0.x * k0.x + q0.y * k0.y + q0.z * k0.z + q0.w * k0.w
                + q1.x * k1.x + q1.y * k1.y + q1.z * k1.z + q1.w * k1.w;
        p += __shfl_xor(p, 1);
        p += __shfl_xor(p, 2);
        p += __shfl_xor(p, 4);
        sc[w] = p * scale_inv;
    }

    float m = sc[0];
    #pragma unroll
    for (int w = 1; w < WW; ++w) m = fmaxf(m, sc[w]);
    float pr[WW];
    float sum = 0.0f;
    #pragma unroll
    for (int w = 0; w < WW; ++w) { pr[w] = expf(sc[w] - m); sum += pr[w]; }
    const float inv = 1.0f / sum;

    float o[8] = {0.f, 0.f, 0.f, 0.f, 0.f, 0.f, 0.f, 0.f};
    #pragma unroll
    for (int w = 0; w < WW; ++w) {
        const uint4 vv = *reinterpret_cast<const uint4*>(&V[bbase + (size_t)sidx[w] * DD + lane * 8]);
        o[0] += pr[w] * bf2f(vv.x & 0xffffu); o[1] += pr[w] * bf2f(vv.x >> 16);
        o[2] += pr[w] * bf2f(vv.y & 0xffffu); o[3] += pr[w] * bf2f(vv.y >> 16);
        o[4] += pr[w] * bf2f(vv.z & 0xffffu); o[5] += pr[w] * bf2f(vv.z >> 16);
        o[6] += pr[w] * bf2f(vv.w & 0xffffu); o[7] += pr[w] * bf2f(vv.w >> 16);
    }
    uintT rh[8], rl[8];
    #pragma unroll
    for (int i = 0; i < 8; ++i) {
        const float val = o[i] * inv;
        uintT h = f2bf(val);
        rh[i] = h;
        rl[i] = f2bf(val - bf2f(h));
    }
    uint4 oh, ol;
    oh.x = rh[0] | (rh[1] << 16); oh.y = rh[2] | (rh[3] << 16);
    oh.z = rh[4] | (rh[5] << 16); oh.w = rh[6] | (rh[7] << 16);
    ol.x = rl[0] | (rl[1] << 16); ol.y = rl[2] | (rl[3] << 16);
    ol.z = rl[4] | (rl[5] << 16); ol.w = rl[6] | (rl[7] << 16);
    *reinterpret_cast<uint4*>(&AOh[rowbase]) = oh;
    *reinterpret_cast<uint4*>(&AOl[rowbase]) = ol;
}

// ---------------- Launcher ----------------
extern "C" void kernel_launch(void* const* d_in, const int* in_sizes, int n_in,
                              void* d_out, int out_size, void* d_ws, size_t ws_size,
                              hipStream_t stream) {
    const float* x    = (const float*)d_in[0];
    const float* Wq   = (const float*)d_in[1];
    const float* bq   = (const float*)d_in[2];
    const float* Wk   = (const float*)d_in[3];
    const float* bk   = (const float*)d_in[4];
    const float* Wv   = (const float*)d_in[5];
    const float* bv   = (const float*)d_in[6];
    const float* Wo   = (const float*)d_in[7];
    const float* bo   = (const float*)d_in[8];
    const float* temp = (const float*)d_in[9];
    float* out = (float*)d_out;

    const int B = in_sizes[0] / (TT * DD);   // 2
    const int M = B * TT;                    // 8192
    const size_t MD = (size_t)M * DD;

    float* Qb = (float*)d_ws;                          // fp32
    float* Kb = Qb + MD;                               // fp32
    ushortT* Vb = (ushortT*)(Kb + MD);                 // bf16
    ushortT* AOh = Vb + MD;
    ushortT* AOl = AOh + MD;
    ushortT* Wqh = AOl + MD;
    ushortT* Wql = Wqh + DD * DD;
    ushortT* Wkh = Wql + DD * DD;
    ushortT* Wkl = Wkh + DD * DD;
    ushortT* Wvh = Wkl + DD * DD;
    ushortT* Wvl = Wvh + DD * DD;
    ushortT* Woh = Wvl + DD * DD;
    ushortT* Wol = Woh + DD * DD;
    int* kvg   = (int*)(Wol + DD * DD);
    int* table = kvg + TT;
    int* cntg  = table + 256 * WW;
    int* f16g  = cntg + 256;

    routes_f16_kernel<<<256, 256, 0, stream>>>(kvg, cntg, f16g);
    routes_merge_kernel<<<1, 256, 0, stream>>>(cntg, f16g, table);
    convw_tile_kernel<<<dim3(4, 16, 4), 256, 0, stream>>>(Wq, Wk, Wv, Wo,
                                                          Wqh, Wql, Wkh, Wkl,
                                                          Wvh, Wvl, Woh, Wol);

    qkv_gemm<<<QKV_NWG, 256, 0, stream>>>(x, Wqh, Wql, Wkh, Wkl, Wvh, Wvl,
                                          bq, bk, bv, Qb, Kb, Vb, M);

    attn2_kernel<<<(M * 64) / 256, 256, 0, stream>>>(Qb, Kb, Vb, kvg, table, temp, AOh, AOl, B);

    out_gemm<<<OUT_NWG, 256, 0, stream>>>(AOh, AOl, Woh, Wol, bo, out, M);
}

// Round 20
// 142.320 us; speedup vs baseline: 1.0367x; 1.0015x over previous
//
#include <hip/hip_runtime.h>
#include <hip/hip_bf16.h>
#include <cstdint>
#include <climits>

#define TT 4096
#define DD 512
#define HH 8
#define HD 64
#define WW 16
#define CDEPTH 8

typedef unsigned short ushortT;
typedef unsigned int uintT;
using bf16x8 = __attribute__((ext_vector_type(8))) short;
using f32x4  = __attribute__((ext_vector_type(4))) float;

static __device__ __forceinline__ uintT f2bf(float v) {
    __hip_bfloat16 h = __float2bfloat16(v);
    return (uintT)*reinterpret_cast<ushortT*>(&h);
}
static __device__ __forceinline__ float bf2f(uintT u) {
    return __uint_as_float(u << 16);
}

// Swizzled LDS index (in shorts) for [row][32 shorts] tiles merged as 128B super-rows.
// r = logical row, c = 16B-chunk index (0..3). Bijective; verified conflict-free
// (SQ_LDS_BANK_CONFLICT 9.4M -> 0, rounds 9/11/13/14/16/19).
static __device__ __forceinline__ int swz_idx(int r, int c) {
    const int u = r >> 1;
    const int s = (((r & 1) << 2) | c) ^ (u & 7);
    return (u << 6) + (s << 3);   // u*64 shorts + s*8 shorts
}
// Inverse: 16B-slot p -> (r,c). Verified: swz_idx(r,c)/8 == p round-trips.
static __device__ __forceinline__ void inv_swz(int p, int& r, int& c) {
    const int u = p >> 3;
    const int bits = (p & 7) ^ (u & 7);
    r = (u << 1) | (bits >> 2);
    c = bits & 3;
}

// Async global->LDS 16B copy: per-lane global src, wave-uniform LDS base (+lane*16 by HW).
#define GLDS(gsrc, ldst)                                                          \
    __builtin_amdgcn_global_load_lds(                                             \
        (const __attribute__((address_space(1))) uint32_t*)(gsrc),                \
        (__attribute__((address_space(3))) uint32_t*)(ldst), 16, 0, 0)

static __device__ __forceinline__ int cantor_m(int t) {
    float x = (float)t / (float)(TT - 1);
    x = fminf(fmaxf(x, 1e-6f), 1.0f - 1e-6f);
    int m = 0;
    #pragma unroll
    for (int i = 0; i < CDEPTH; ++i) {
        float x3 = x * 3.0f;
        float dg = floorf(x3);
        x = x3 - dg;
        m = (m << 1) | ((dg == 2.0f) ? 1 : 0);
    }
    return m;
}

// ---------------- Routes kernel A: per-bucket first-16 + counts (256 blocks) ----------------
__global__ __launch_bounds__(256) void routes_f16_kernel(int* __restrict__ kv_g,
                                                         int* __restrict__ cnt_g,
                                                         int* __restrict__ f16_g) {
    __shared__ int kvloc[TT];
    __shared__ int pscan[256];
    const int tid = threadIdx.x;
    const int b = blockIdx.x;

    #pragma unroll
    for (int i = 0; i < 16; ++i) {
        const int t = i * 256 + tid;
        kvloc[t] = cantor_m(t);
    }
    __syncthreads();

    if (tid < 16) kv_g[b * 16 + tid] = kvloc[b * 16 + tid];

    int localcnt = 0;
    #pragma unroll
    for (int i = 0; i < 16; ++i)
        localcnt += (kvloc[tid * 16 + i] == b) ? 1 : 0;

    pscan[tid] = localcnt;
    __syncthreads();
    #pragma unroll
    for (int off = 1; off < 256; off <<= 1) {
        int v = (tid >= off) ? pscan[tid - off] : 0;
        __syncthreads();
        pscan[tid] += v;
        __syncthreads();
    }
    const int excl = pscan[tid] - localcnt;

    int r = excl;
    #pragma unroll
    for (int i = 0; i < 16; ++i) {
        const int t = tid * 16 + i;
        if (kvloc[t] == b) {
            if (r < 16) f16_g[b * 16 + r] = t;
            ++r;
        }
    }
    if (tid == 255) cnt_g[b] = pscan[255];
}

// ---------------- Routes kernel B: ring-merge selection per bucket (1 block) ----------------
__global__ __launch_bounds__(256) void routes_merge_kernel(const int* __restrict__ cnt_g,
                                                           const int* __restrict__ f16_g,
                                                           int* __restrict__ table) {
    __shared__ int cnt[256];
    __shared__ int f16[256][16];
    const int tid = threadIdx.x;
    cnt[tid] = cnt_g[tid];
    {
        int4 a = reinterpret_cast<const int4*>(f16_g)[tid * 4 + 0];
        int4 b4 = reinterpret_cast<const int4*>(f16_g)[tid * 4 + 1];
        int4 c4 = reinterpret_cast<const int4*>(f16_g)[tid * 4 + 2];
        int4 d4 = reinterpret_cast<const int4*>(f16_g)[tid * 4 + 3];
        f16[tid][0] = a.x;  f16[tid][1] = a.y;  f16[tid][2] = a.z;  f16[tid][3] = a.w;
        f16[tid][4] = b4.x; f16[tid][5] = b4.y; f16[tid][6] = b4.z; f16[tid][7] = b4.w;
        f16[tid][8] = c4.x; f16[tid][9] = c4.y; f16[tid][10] = c4.z; f16[tid][11] = c4.w;
        f16[tid][12] = d4.x; f16[tid][13] = d4.y; f16[tid][14] = d4.z; f16[tid][15] = d4.w;
    }
    __syncthreads();

    int rtl[WW];
    int n = 0;
    {
        int c = cnt[tid];
        int take = (c < WW) ? c : WW;
        for (int i = 0; i < take; ++i) rtl[n++] = f16[tid][i];
    }
    for (int d = 1; n < WW && d <= 256; ++d) {
        const int lo = tid - d, hi = tid + d;
        const int clo = (lo >= 0) ? cnt[lo] : 0;
        const int chi = (hi < 256) ? cnt[hi] : 0;
        const int need = WW - n;
        if (clo + chi <= need) {
            for (int i = 0; i < clo; ++i) rtl[n++] = f16[lo][i];
            for (int i = 0; i < chi; ++i) rtl[n++] = f16[hi][i];
        } else {
            const int cl = (clo < WW) ? clo : WW;
            const int ch = (chi < WW) ? chi : WW;
            int i = 0, j = 0;
            while (n < WW) {
                int a = (i < cl) ? f16[lo][i] : INT_MAX;
                int b = (j < ch) ? f16[hi][j] : INT_MAX;
                if (a < b) { rtl[n++] = a; ++i; }
                else       { rtl[n++] = b; ++j; }
            }
        }
    }
    #pragma unroll
    for (int i = 0; i < WW; ++i) table[tid * WW + i] = rtl[i];
}

// ---------------- W[k][n] -> pre-swizzled bf16 hi/lo tiles ----------------
// Layout per weight: [nt 0..3][kt 0..15][slot 0..511] of 16B chunks, where slot
// index equals swz_idx(r,c)/8 for chunk (row r in tile, k-chunk c). This lets the
// GEMMs stage B with linear global_load_lds while keeping the swizzled reads.
__global__ __launch_bounds__(256) void convw_tile_kernel(
        const float* __restrict__ W0, const float* __restrict__ W1,
        const float* __restrict__ W2, const float* __restrict__ W3,
        ushortT* __restrict__ H0, ushortT* __restrict__ L0,
        ushortT* __restrict__ H1, ushortT* __restrict__ L1,
        ushortT* __restrict__ H2, ushortT* __restrict__ L2,
        ushortT* __restrict__ H3, ushortT* __restrict__ L3) {
    const float* src; ushortT* dh; ushortT* dl;
    switch (blockIdx.z) {
        case 0: src = W0; dh = H0; dl = L0; break;
        case 1: src = W1; dh = H1; dl = L1; break;
        case 2: src = W2; dh = H2; dl = L2; break;
        default: src = W3; dh = H3; dl = L3; break;
    }
    const int nt = blockIdx.x;           // 0..3
    const int kt = blockIdx.y;           // 0..15
    const size_t tilebase = ((size_t)(nt * 16 + kt)) * 4096;  // shorts (512 slots * 8)

    #pragma unroll
    for (int s = 0; s < 2; ++s) {
        const int p = threadIdx.x + s * 256;   // slot 0..511
        int r, c;
        inv_swz(p, r, c);
        const int n = nt * 128 + r;
        const int k = kt * 32 + c * 8;
        uintT rh[8], rl[8];
        #pragma unroll
        for (int j = 0; j < 8; ++j) {
            const float f = src[(size_t)(k + j) * DD + n];
            const uintT h = f2bf(f);
            rh[j] = h;
            rl[j] = f2bf(f - bf2f(h));
        }
        uint4 oh, ol;
        oh.x = rh[0] | (rh[1] << 16); oh.y = rh[2] | (rh[3] << 16);
        oh.z = rh[4] | (rh[5] << 16); oh.w = rh[6] | (rh[7] << 16);
        ol.x = rl[0] | (rl[1] << 16); ol.y = rl[2] | (rl[3] << 16);
        ol.z = rl[4] | (rl[5] << 16); ol.w = rl[6] | (rl[7] << 16);
        *reinterpret_cast<uint4*>(&dh[tilebase + (size_t)p * 8]) = oh;
        *reinterpret_cast<uint4*>(&dl[tilebase + (size_t)p * 8]) = ol;
    }
}

// ---------------- Fused QKV GEMM: 64x128 tile, BK=32, split-bf16 3-term ----------------
// B staged via global_load_lds from pre-swizzled W tiles (linear copy); A reg-staged
// with inline fp32->hi/lo split. XCD swizzle + LDS XOR-swizzle as verified.
// Best verified configuration: 142.5-142.8 us total (rounds 14/16/19).
#define QBM 64
#define QBN 128
#define QBK 32
#define QKV_NWG 1536
#define OUT_NWG 512

__global__ __launch_bounds__(256, 6) void qkv_gemm(const float* __restrict__ x,
        const ushortT* __restrict__ Wqh, const ushortT* __restrict__ Wql,
        const ushortT* __restrict__ Wkh, const ushortT* __restrict__ Wkl,
        const ushortT* __restrict__ Wvh, const ushortT* __restrict__ Wvl,
        const float* __restrict__ bq, const float* __restrict__ bk, const float* __restrict__ bv,
        float* __restrict__ Qo, float* __restrict__ Ko, ushortT* __restrict__ Vo, int M) {
    __shared__ short Ash[QBM * QBK];        // 4 KB, swizzled
    __shared__ short Asl[QBM * QBK];
    __shared__ short Bsh[QBN * QBK];        // 8 KB, swizzled (slot-linear from W')
    __shared__ short Bsl[QBN * QBK];
    const int tid = threadIdx.x;
    const int lane = tid & 63;
    const int wid = tid >> 6;

    // T1 bijective XCD swizzle (nwg % 8 == 0): same-XCD blocks share bm-range.
    const int id = blockIdx.x;
    const int swz = (id & 7) * (QKV_NWG / 8) + (id >> 3);
    const int bm = (swz / 12) * QBM;
    const int bnG = (swz % 12) * QBN;       // 0..1535
    const int seg = bnG >> 9;               // 0=Q 1=K 2=V
    const int bn = bnG & 511;
    const ushortT* __restrict__ Bhp = (seg == 0) ? Wqh : (seg == 1) ? Wkh : Wvh;
    const ushortT* __restrict__ Blp = (seg == 0) ? Wql : (seg == 1) ? Wkl : Wvl;
    const float* __restrict__ bias = (seg == 0) ? bq : (seg == 1) ? bk : bv;

    const int wr = wid >> 1;                // 0..1 : 32-row slab
    const int wc = wid & 1;                 // 0..1 : 64-col slab

    f32x4 acc[2][4];
    #pragma unroll
    for (int i = 0; i < 2; ++i)
        #pragma unroll
        for (int j = 0; j < 4; ++j)
            acc[i][j] = (f32x4){0.f, 0.f, 0.f, 0.f};

    const int arow = tid >> 2;              // 0..63
    const int achk = tid & 3;               // 16B chunk
    const int fr = lane & 15;
    const int kq = lane >> 4;               // fragment 16B chunk
    const int nt = bn >> 7;                 // W' tile column index

    for (int k0 = 0; k0 < DD; k0 += QBK) {
        // B staging: async identity copy of the pre-swizzled 8 KB tile (per buffer)
        {
            const size_t tb = ((size_t)(nt * 16 + (k0 >> 5))) * 4096;  // shorts
            const int base = wid * 128;     // 128 slots per wave
            #pragma unroll
            for (int q = 0; q < 2; ++q) {
                const size_t so = tb + (size_t)(base + q * 64 + lane) * 8;
                GLDS(&Bhp[so], &Bsh[(base + q * 64) * 8]);
                GLDS(&Blp[so], &Bsl[(base + q * 64) * 8]);
            }
        }
        // A staging: fp32 -> hi/lo bf16 (identical arithmetic), swizzled ds_write
        {
            const float* srcp = &x[(size_t)(bm + arow) * DD + k0 + achk * 8];
            const float4 v0 = *reinterpret_cast<const float4*>(srcp);
            const float4 v1 = *reinterpret_cast<const float4*>(srcp + 4);
            const float vv[8] = {v0.x, v0.y, v0.z, v0.w, v1.x, v1.y, v1.z, v1.w};
            bf16x8 vh, vl;
            #pragma unroll
            for (int j = 0; j < 8; ++j) {
                uintT h = f2bf(vv[j]);
                vh[j] = (short)h;
                vl[j] = (short)f2bf(vv[j] - bf2f(h));
            }
            const int ai = swz_idx(arow, achk);
            *reinterpret_cast<bf16x8*>(&Ash[ai]) = vh;
            *reinterpret_cast<bf16x8*>(&Asl[ai]) = vl;
        }
        __syncthreads();
        {
            bf16x8 avh[2], avl[2], bvh[4], bvl[4];
            #pragma unroll
            for (int i = 0; i < 2; ++i) {
                const int ai = swz_idx(wr * 32 + i * 16 + fr, kq);
                avh[i] = *reinterpret_cast<const bf16x8*>(&Ash[ai]);
                avl[i] = *reinterpret_cast<const bf16x8*>(&Asl[ai]);
            }
            #pragma unroll
            for (int j = 0; j < 4; ++j) {
                const int bi = swz_idx(wc * 64 + j * 16 + fr, kq);
                bvh[j] = *reinterpret_cast<const bf16x8*>(&Bsh[bi]);
                bvl[j] = *reinterpret_cast<const bf16x8*>(&Bsl[bi]);
            }
            #pragma unroll
            for (int i = 0; i < 2; ++i)
                #pragma unroll
                for (int j = 0; j < 4; ++j) {
                    acc[i][j] = __builtin_amdgcn_mfma_f32_16x16x32_bf16(avh[i], bvh[j], acc[i][j], 0, 0, 0);
                    acc[i][j] = __builtin_amdgcn_mfma_f32_16x16x32_bf16(avl[i], bvh[j], acc[i][j], 0, 0, 0);
                    acc[i][j] = __builtin_amdgcn_mfma_f32_16x16x32_bf16(avh[i], bvl[j], acc[i][j], 0, 0, 0);
                }
        }
        __syncthreads();
    }

    const int fq = lane >> 4;
    #pragma unroll
    for (int j = 0; j < 4; ++j) {
        const int col = bn + wc * 64 + j * 16 + fr;
        const float bvv = bias[col];
        #pragma unroll
        for (int i = 0; i < 2; ++i) {
            const int row0 = bm + wr * 32 + i * 16 + fq * 4;
            #pragma unroll
            for (int r = 0; r < 4; ++r) {
                const float val = acc[i][j][r] + bvv;
                if (seg == 2) {
                    Vo[(size_t)(row0 + r) * DD + col] = (ushortT)f2bf(val);
                } else {
                    float* dst = seg ? Ko : Qo;
                    dst[(size_t)(row0 + r) * DD + col] = val;
                }
            }
        }
    }
}

// ---------------- Output GEMM: A = AO hi/lo bf16 (reg-staged), B = Wo pre-swizzled ----------------
__global__ __launch_bounds__(256, 6) void out_gemm(const ushortT* __restrict__ Ahg,
                                                   const ushortT* __restrict__ Alg,
                                                   const ushortT* __restrict__ Bh,
                                                   const ushortT* __restrict__ Bl,
                                                   const float* __restrict__ bias,
                                                   float* __restrict__ C, int M) {
    __shared__ short Ash[QBM * QBK];
    __shared__ short Asl[QBM * QBK];
    __shared__ short Bsh[QBN * QBK];
    __shared__ short Bsl[QBN * QBK];
    const int tid = threadIdx.x;
    const int lane = tid & 63;
    const int wid = tid >> 6;

    const int id = blockIdx.x;
    const int swz = (id & 7) * (OUT_NWG / 8) + (id >> 3);
    const int bm = (swz >> 2) * QBM;
    const int bn = (swz & 3) * QBN;
    const int wr = wid >> 1;
    const int wc = wid & 1;

    f32x4 acc[2][4];
    #pragma unroll
    for (int i = 0; i < 2; ++i)
        #pragma unroll
        for (int j = 0; j < 4; ++j)
            acc[i][j] = (f32x4){0.f, 0.f, 0.f, 0.f};

    const int arow = tid >> 2;
    const int achk = tid & 3;
    const int fr = lane & 15;
    const int kq = lane >> 4;
    const int nt = bn >> 7;

    for (int k0 = 0; k0 < DD; k0 += QBK) {
        // B staging: async identity copy of pre-swizzled Wo tile
        {
            const size_t tb = ((size_t)(nt * 16 + (k0 >> 5))) * 4096;
            const int base = wid * 128;
            #pragma unroll
            for (int q = 0; q < 2; ++q) {
                const size_t so = tb + (size_t)(base + q * 64 + lane) * 8;
                GLDS(&Bh[so], &Bsh[(base + q * 64) * 8]);
                GLDS(&Bl[so], &Bsl[(base + q * 64) * 8]);
            }
        }
        // A staging: reg path (linear rows), swizzled ds_write
        {
            const size_t g = (size_t)(bm + arow) * DD + k0 + achk * 8;
            const int ai = swz_idx(arow, achk);
            *reinterpret_cast<bf16x8*>(&Ash[ai]) = *reinterpret_cast<const bf16x8*>(&Ahg[g]);
            *reinterpret_cast<bf16x8*>(&Asl[ai]) = *reinterpret_cast<const bf16x8*>(&Alg[g]);
        }
        __syncthreads();
        {
            bf16x8 avh[2], avl[2], bvh[4], bvl[4];
            #pragma unroll
            for (int i = 0; i < 2; ++i) {
                const int ai = swz_idx(wr * 32 + i * 16 + fr, kq);
                avh[i] = *reinterpret_cast<const bf16x8*>(&Ash[ai]);
                avl[i] = *reinterpret_cast<const bf16x8*>(&Asl[ai]);
            }
            #pragma unroll
            for (int j = 0; j < 4; ++j) {
                const int bi = swz_idx(wc * 64 + j * 16 + fr, kq);
                bvh[j] = *reinterpret_cast<const bf16x8*>(&Bsh[bi]);
                bvl[j] = *reinterpret_cast<const bf16x8*>(&Bsl[bi]);
            }
            #pragma unroll
            for (int i = 0; i < 2; ++i)
                #pragma unroll
                for (int j = 0; j < 4; ++j) {
                    acc[i][j] = __builtin_amdgcn_mfma_f32_16x16x32_bf16(avh[i], bvh[j], acc[i][j], 0, 0, 0);
                    acc[i][j] = __builtin_amdgcn_mfma_f32_16x16x32_bf16(avl[i], bvh[j], acc[i][j], 0, 0, 0);
                    acc[i][j] = __builtin_amdgcn_mfma_f32_16x16x32_bf16(avh[i], bvl[j], acc[i][j], 0, 0, 0);
                }
        }
        __syncthreads();
    }

    const int fq = lane >> 4;
    #pragma unroll
    for (int j = 0; j < 4; ++j) {
        const int col = bn + wc * 64 + j * 16 + fr;
        const float bvv = bias[col];
        #pragma unroll
        for (int i = 0; i < 2; ++i) {
            const int row0 = bm + wr * 32 + i * 16 + fq * 4;
            #pragma unroll
            for (int r = 0; r < 4; ++r)
                C[(size_t)(row0 + r) * DD + col] = acc[i][j][r] + bvv;
        }
    }
}

// ---------------- Attention: one wave per (b,t), all 8 heads; V bf16; AO hi/lo ----------------
__global__ __launch_bounds__(256) void attn2_kernel(const float* __restrict__ Q,
                                                    const float* __restrict__ K,
                                                    const ushortT* __restrict__ V,
                                                    const int* __restrict__ kv_g,
                                                    const int* __restrict__ table,
                                                    const float* __restrict__ temp_ptr,
                                                    ushortT* __restrict__ AOh,
                                                    ushortT* __restrict__ AOl, int B) {
    const int lane = threadIdx.x & 63;
    const int u = (blockIdx.x * blockDim.x + threadIdx.x) >> 6;  // b*TT + t
    if (u >= B * TT) return;
    const int t = u & (TT - 1);
    const float scale_inv = 1.0f / (8.0f * fabsf(temp_ptr[0]));

    const int* rt = &table[kv_g[t] * WW];
    int sidx[WW];
    #pragma unroll
    for (int w = 0; w < WW; ++w) sidx[w] = rt[w];

    const size_t rowbase = (size_t)u * DD + lane * 8;
    const size_t bbase = (size_t)(u - t) * DD;
    const float4 q0 = *reinterpret_cast<const float4*>(&Q[rowbase]);
    const float4 q1 = *reinterpret_cast<const float4*>(&Q[rowbase + 4]);

    float sc[WW];
    #pragma unroll
    for (int w = 0; w < WW; ++w) {
        const float* kr = &K[bbase + (size_t)sidx[w] * DD + lane * 8];
        const float4 k0 = *reinterpret_cast<const float4*>(kr);
        const float4 k1 = *reinterpret_cast<const float4*>(kr + 4);
        float p = q0.x * k0.x + q0.y * k0.y + q0.z * k0.z + q0.w * k0.w
                + q1.x * k1.x + q1.y * k1.y + q1.z * k1.z + q1.w * k1.w;
        p += __shfl_xor(p, 1);
        p += __shfl_xor(p, 2);
        p += __shfl_xor(p, 4);
        sc[w] = p * scale_inv;
    }

    float m = sc[0];
    #pragma unroll
    for (int w = 1; w < WW; ++w) m = fmaxf(m, sc[w]);
    float pr[WW];
    float sum = 0.0f;
    #pragma unroll
    for (int w = 0; w < WW; ++w) { pr[w] = expf(sc[w] - m); sum += pr[w]; }
    const float inv = 1.0f / sum;

    float o[8] = {0.f, 0.f, 0.f, 0.f, 0.f, 0.f, 0.f, 0.f};
    #pragma unroll
    for (int w = 0; w < WW; ++w) {
        const uint4 vv = *reinterpret_cast<const uint4*>(&V[bbase + (size_t)sidx[w] * DD + lane * 8]);
        o[0] += pr[w] * bf2f(vv.x & 0xffffu); o[1] += pr[w] * bf2f(vv.x >> 16);
        o[2] += pr[w] * bf2f(vv.y & 0xffffu); o[3] += pr[w] * bf2f(vv.y >> 16);
        o[4] += pr[w] * bf2f(vv.z & 0xffffu); o[5] += pr[w] * bf2f(vv.z >> 16);
        o[6] += pr[w] * bf2f(vv.w & 0xffffu); o[7] += pr[w] * bf2f(vv.w >> 16);
    }
    uintT rh[8], rl[8];
    #pragma unroll
    for (int i = 0; i < 8; ++i) {
        const float val = o[i] * inv;
        uintT h = f2bf(val);
        rh[i] = h;
        rl[i] = f2bf(val - bf2f(h));
    }
    uint4 oh, ol;
    oh.x = rh[0] | (rh[1] << 16); oh.y = rh[2] | (rh[3] << 16);
    oh.z = rh[4] | (rh[5] << 16); oh.w = rh[6] | (rh[7] << 16);
    ol.x = rl[0] | (rl[1] << 16); ol.y = rl[2] | (rl[3] << 16);
    ol.z = rl[4] | (rl[5] << 16); ol.w = rl[6] | (rl[7] << 16);
    *reinterpret_cast<uint4*>(&AOh[rowbase]) = oh;
    *reinterpret_cast<uint4*>(&AOl[rowbase]) = ol;
}

// ---------------- Launcher ----------------
extern "C" void kernel_launch(void* const* d_in, const int* in_sizes, int n_in,
                              void* d_out, int out_size, void* d_ws, size_t ws_size,
                              hipStream_t stream) {
    const float* x    = (const float*)d_in[0];
    const float* Wq   = (const float*)d_in[1];
    const float* bq   = (const float*)d_in[2];
    const float* Wk   = (const float*)d_in[3];
    const float* bk   = (const float*)d_in[4];
    const float* Wv   = (const float*)d_in[5];
    const float* bv   = (const float*)d_in[6];
    const float* Wo   = (const float*)d_in[7];
    const float* bo   = (const float*)d_in[8];
    const float* temp = (const float*)d_in[9];
    float* out = (float*)d_out;

    const int B = in_sizes[0] / (TT * DD);   // 2
    const int M = B * TT;                    // 8192
    const size_t MD = (size_t)M * DD;

    float* Qb = (float*)d_ws;                          // fp32
    float* Kb = Qb + MD;                               // fp32
    ushortT* Vb = (ushortT*)(Kb + MD);                 // bf16
    ushortT* AOh = Vb + MD;
    ushortT* AOl = AOh + MD;
    ushortT* Wqh = AOl + MD;
    ushortT* Wql = Wqh + DD * DD;
    ushortT* Wkh = Wql + DD * DD;
    ushortT* Wkl = Wkh + DD * DD;
    ushortT* Wvh = Wkl + DD * DD;
    ushortT* Wvl = Wvh + DD * DD;
    ushortT* Woh = Wvl + DD * DD;
    ushortT* Wol = Woh + DD * DD;
    int* kvg   = (int*)(Wol + DD * DD);
    int* table = kvg + TT;
    int* cntg  = table + 256 * WW;
    int* f16g  = cntg + 256;

    routes_f16_kernel<<<256, 256, 0, stream>>>(kvg, cntg, f16g);
    routes_merge_kernel<<<1, 256, 0, stream>>>(cntg, f16g, table);
    convw_tile_kernel<<<dim3(4, 16, 4), 256, 0, stream>>>(Wq, Wk, Wv, Wo,
                                                          Wqh, Wql, Wkh, Wkl,
                                                          Wvh, Wvl, Woh, Wol);

    qkv_gemm<<<QKV_NWG, 256, 0, stream>>>(x, Wqh, Wql, Wkh, Wkl, Wvh, Wvl,
                                          bq, bk, bv, Qb, Kb, Vb, M);

    attn2_kernel<<<(M * 64) / 256, 256, 0, stream>>>(Qb, Kb, Vb, kvg, table, temp, AOh, AOl, B);

    out_gemm<<<OUT_NWG, 256, 0, stream>>>(AOh, AOl, Woh, Wol, bo, out, M);
}